// Round 1
// baseline (90.410 us; speedup 1.0000x reference)
//
#include <hip/hip_runtime.h>
#include <math.h>

// ---------------- ws layout (float indices) ----------------
#define WS_MU    0                    // 64 floats: raw per-(n,c) sums (mean = /65536)
#define WS_CMIN  64                   // 4 ordered-uint: per-sample cos min
#define WS_CMAX  68                   // 4 ordered-uint: per-sample cos max
#define WS_COMAX 72                   // 1 raw-bits uint: global max of left*right (>=0)
#define WS_COS   128                  // 4*65536 floats
#define WS_GP    (WS_COS + 262144)    // 256 blocks * 256 floats: Gram partials
#define WS_H2    (WS_GP + 65536)      // 4*128*256 floats
#define WS_H3    (WS_H2 + 131072)     // 4*128*256 floats
#define WS_S     (WS_H3 + 131072)     // 512 floats

// ---------------- wave-64 reductions ----------------
__device__ __forceinline__ float wrSum(float v){
#pragma unroll
  for(int o = 32; o > 0; o >>= 1) v += __shfl_down(v, o, 64);
  return v;
}
__device__ __forceinline__ float wrMax(float v){
#pragma unroll
  for(int o = 32; o > 0; o >>= 1) v = fmaxf(v, __shfl_down(v, o, 64));
  return v;
}
__device__ __forceinline__ float wrMin(float v){
#pragma unroll
  for(int o = 32; o > 0; o >>= 1) v = fminf(v, __shfl_down(v, o, 64));
  return v;
}
// order-preserving float<->uint for atomic min/max on signed floats
__device__ __forceinline__ unsigned encOrd(float f){
  unsigned u = __float_as_uint(f);
  return (u & 0x80000000u) ? ~u : (u | 0x80000000u);
}
__device__ __forceinline__ float decOrd(unsigned e){
  return __uint_as_float((e & 0x80000000u) ? (e ^ 0x80000000u) : ~e);
}

// ---------------- K0: reset atomics ----------------
__global__ void k_init(float* __restrict__ ws){
  const int t = threadIdx.x;
  if(t < 64) ws[WS_MU + t] = 0.0f;
  unsigned* u = (unsigned*)ws;
  if(t < 4){ u[WS_CMIN + t] = 0xFFFFFFFFu; u[WS_CMAX + t] = 0u; }
  if(t == 0) u[WS_COMAX] = 0u;
}

// ---------------- K1: per-(n,c) channel sums ----------------
__global__ __launch_bounds__(256) void k_mu(const float* __restrict__ x, float* __restrict__ ws){
  const int plane = blockIdx.x >> 2;     // n*16+c, 0..63
  const int quarter = blockIdx.x & 3;
  const float4* xp = (const float4*)(x + plane*65536 + quarter*16384);
  const int t = threadIdx.x;
  float s = 0.0f;
#pragma unroll
  for(int k = 0; k < 16; ++k){
    float4 v4 = xp[t + k*256];
    s += (v4.x + v4.y) + (v4.z + v4.w);
  }
  __shared__ float red[4];
  s = wrSum(s);
  if((t & 63) == 0) red[t >> 6] = s;
  __syncthreads();
  if(t == 0) atomicAdd(ws + WS_MU + plane, (red[0]+red[1])+(red[2]+red[3]));
}

// ---------------- K2: cos field + per-sample min/max ----------------
__global__ __launch_bounds__(256) void k_cos(const float* __restrict__ x, float* __restrict__ ws){
  const int t = threadIdx.x;
  const int n = blockIdx.x >> 8;
  const int p = ((blockIdx.x & 255) << 8) + t;
  float mn[16]; float nn = 0.0f;
#pragma unroll
  for(int c = 0; c < 16; ++c){
    float m = ws[WS_MU + n*16 + c] * (1.0f/65536.0f);
    mn[c] = m; nn += m*m;
  }
  const float inv = 1.0f / fmaxf(sqrtf(nn), 1e-12f);
  const float* xp = x + n*1048576 + p;
  float dot = 0.0f, xx = 0.0f;
#pragma unroll
  for(int c = 0; c < 16; ++c){
    float v = xp[c*65536];
    dot += v * mn[c];
    xx  += v * v;
  }
  const float cosv = dot * inv / fmaxf(sqrtf(xx), 1e-12f);
  ws[WS_COS + n*65536 + p] = cosv;
  float lo = wrMin(cosv), hi = wrMax(cosv);
  __shared__ float rlo[4], rhi[4];
  if((t & 63) == 0){ rlo[t>>6] = lo; rhi[t>>6] = hi; }
  __syncthreads();
  if(t == 0){
    float a = fminf(fminf(rlo[0], rlo[1]), fminf(rlo[2], rlo[3]));
    float b = fmaxf(fmaxf(rhi[0], rhi[1]), fmaxf(rhi[2], rhi[3]));
    atomicMin((unsigned*)ws + WS_CMIN + n, encOrd(a));
    atomicMax((unsigned*)ws + WS_CMAX + n, encOrd(b));
  }
}

// ---------------- K3: quant + 16x16 Gram partials + global co-max ----------------
__global__ __launch_bounds__(256) void k_gram(float* __restrict__ ws){
  __shared__ float Lsh[5120];   // 256 pixels * stride 20
  __shared__ float Rsh[5120];
  __shared__ float rmp[4];
  const int t = threadIdx.x;
  const int n = blockIdx.x >> 6;
  const int h0 = (blockIdx.x & 63) << 2;   // 4 rows per block
  const float* cosp = ws + WS_COS + n * 65536;
  const unsigned* uw = (const unsigned*)ws;
  const float cmin = decOrd(uw[WS_CMIN + n]);
  const float cmax = decOrd(uw[WS_CMAX + n]);
  const float dq = cmax - cmin;
  float q[16];
#pragma unroll
  for(int l = 0; l < 16; ++l) q[l] = (float)(2*l+1) * (1.0f/32.0f) * dq + cmin;

  const int m  = t & 15;         // tile id within group
  const int g  = t >> 4;         // group id (pixel partition)
  const int i0 = (m >> 2) << 2;
  const int j0 = (m & 3) << 2;
  float acc[4][4] = {{0.0f}};
  float mp = 0.0f;

  for(int ch = 0; ch < 4; ++ch){
    const int h = h0 + ch;
    const float cl = cosp[h*256 + t];
    const bool valid = (h < 255) && (t < 255);
    const float cr = valid ? cosp[h*256 + t + 257] : 0.0f;
    float lv[16], rv[16];
    float mL = 0.0f, mR = 0.0f;
#pragma unroll
    for(int l = 0; l < 16; ++l){
      float dl = cl - q[l];
      float Lv = __expf(-32.0f * dl * dl);
      float dr = cr - q[l];
      float Rv = valid ? __expf(-32.0f * dr * dr) : 0.0f;
      lv[l] = Lv; rv[l] = Rv;
      mL = fmaxf(mL, Lv); mR = fmaxf(mR, Rv);
    }
    mp = fmaxf(mp, mL * mR);
    float4* Lp = (float4*)&Lsh[t * 20];
    float4* Rp = (float4*)&Rsh[t * 20];
#pragma unroll
    for(int k = 0; k < 4; ++k){
      Lp[k] = make_float4(lv[4*k], lv[4*k+1], lv[4*k+2], lv[4*k+3]);
      Rp[k] = make_float4(rv[4*k], rv[4*k+1], rv[4*k+2], rv[4*k+3]);
    }
    __syncthreads();
#pragma unroll 4
    for(int it = 0; it < 16; ++it){
      const int p = it * 16 + g;
      const float4 Lx = *(const float4*)&Lsh[p*20 + i0];
      const float4 Rx = *(const float4*)&Rsh[p*20 + j0];
      const float lf[4] = {Lx.x, Lx.y, Lx.z, Lx.w};
      const float rf[4] = {Rx.x, Rx.y, Rx.z, Rx.w};
#pragma unroll
      for(int a = 0; a < 4; ++a)
#pragma unroll
        for(int b = 0; b < 4; ++b) acc[a][b] += lf[a] * rf[b];
    }
    __syncthreads();
  }
  // reduce the 16 pixel-groups' tiles via LDS, write one 256-float partial per block
#pragma unroll
  for(int a = 0; a < 4; ++a)
#pragma unroll
    for(int b = 0; b < 4; ++b)
      Lsh[t*16 + a*4 + b] = acc[a][b];
  __syncthreads();
  const int i = t >> 4, j = t & 15;
  const int mm = ((i >> 2) << 2) + (j >> 2);
  const int idx = mm*16 + (i & 3)*4 + (j & 3);
  float v = 0.0f;
#pragma unroll
  for(int gg = 0; gg < 16; ++gg) v += Lsh[gg*256 + idx];
  ws[WS_GP + blockIdx.x * 256 + t] = v;

  mp = wrMax(mp);
  if((t & 63) == 0) rmp[t >> 6] = mp;
  __syncthreads();
  if(t == 0){
    float vv = fmaxf(fmaxf(rmp[0], rmp[1]), fmaxf(rmp[2], rmp[3]));
    atomicMax((unsigned*)ws + WS_COMAX, __float_as_uint(vv)); // all values >= 0
  }
}

// ---------------- K4: sta + feat + f1(leaky) + f2(relu) -> h2 ----------------
__global__ __launch_bounds__(128) void k_mlp(const float* __restrict__ f1w, const float* __restrict__ f1bp,
                                             const float* __restrict__ f2w, const float* __restrict__ f2bp,
                                             float* __restrict__ ws){
  const int t = threadIdx.x;
  const int n = blockIdx.x >> 8;
  const int pos = blockIdx.x & 255;
  __shared__ float red[2];
  __shared__ float h1[64];
  __shared__ float staSh;
  float v = 0.0f;
  if(t < 64) v = ws[WS_GP + (n*64 + t)*256 + pos];
  v = wrSum(v);
  if((t & 63) == 0) red[t >> 6] = v;
  __syncthreads();
  if(t == 0){
    const unsigned* uw0 = (const unsigned*)ws;
    float comax = __uint_as_float(uw0[WS_COMAX]);
    staSh = (red[0] + red[1]) / (comax + 1e-6f);   // co.min()==0 exactly (zero padding)
  }
  __syncthreads();
  const unsigned* uw = (const unsigned*)ws;
  const float cmin = decOrd(uw[WS_CMIN + n]);
  const float cmax = decOrd(uw[WS_CMAX + n]);
  const float dq = cmax - cmin;
  const int l1 = pos >> 4, l2 = pos & 15;
  const float ft0 = (float)(2*l2+1)*(1.0f/32.0f)*dq + cmin;  // q_h
  const float ft1 = (float)(2*l1+1)*(1.0f/32.0f)*dq + cmin;  // q_w
  const float ft2 = staSh;
  if(t < 64){
    float a = f1w[t*3+0]*ft0 + f1w[t*3+1]*ft1 + f1w[t*3+2]*ft2 + f1bp[t];
    h1[t] = (a > 0.0f) ? a : 0.01f * a;
  }
  __syncthreads();
  float acc = f2bp[t];
#pragma unroll
  for(int c = 0; c < 64; ++c) acc += f2w[t*64 + c] * h1[c];
  acc = fmaxf(acc, 0.0f);
  ws[WS_H2 + n*32768 + t*256 + pos] = acc;
}

// ---------------- K5: o1 conv + BN1 (batch stats) + relu -> h3 ----------------
__global__ __launch_bounds__(256) void k_o1(const float* __restrict__ o1w, const float* __restrict__ o1b,
                                            const float* __restrict__ g1, const float* __restrict__ b1,
                                            float* __restrict__ ws){
  const int ch = blockIdx.x;
  const int t = threadIdx.x;
  __shared__ float wl[144];
  __shared__ float xav[64];
  __shared__ float red[8];
  __shared__ float scSh, shSh;
  if(t < 144) wl[t] = o1w[ch*144 + t];
  if(t < 64) xav[t] = ws[WS_MU + t] * (1.0f/65536.0f);
  __syncthreads();
  float acc[4];
#pragma unroll
  for(int n = 0; n < 4; ++n) acc[n] = o1b[ch];
#pragma unroll
  for(int c = 0; c < 16; ++c){
    float wv = wl[c];
#pragma unroll
    for(int n = 0; n < 4; ++n) acc[n] += wv * xav[n*16 + c];
  }
  for(int c = 0; c < 128; ++c){
    float wv = wl[16 + c];
#pragma unroll
    for(int n = 0; n < 4; ++n) acc[n] += wv * ws[WS_H2 + n*32768 + c*256 + t];
  }
  float s = 0.0f, s2 = 0.0f;
#pragma unroll
  for(int n = 0; n < 4; ++n){ s += acc[n]; s2 += acc[n]*acc[n]; }
  s = wrSum(s); s2 = wrSum(s2);
  if((t & 63) == 0){ red[t>>6] = s; red[4 + (t>>6)] = s2; }
  __syncthreads();
  if(t == 0){
    float S  = red[0]+red[1]+red[2]+red[3];
    float S2 = red[4]+red[5]+red[6]+red[7];
    float mean = S * (1.0f/1024.0f);
    float var = S2 * (1.0f/1024.0f) - mean*mean;
    float sc = g1[ch] * rsqrtf(var + 1e-5f);
    scSh = sc; shSh = b1[ch] - mean*sc;
  }
  __syncthreads();
#pragma unroll
  for(int n = 0; n < 4; ++n)
    ws[WS_H3 + n*32768 + ch*256 + t] = fmaxf(acc[n]*scSh + shSh, 0.0f);
}

// ---------------- K6: o2 conv + BN2 + position-mean -> s ----------------
__global__ __launch_bounds__(256) void k_o2(const float* __restrict__ o2w, const float* __restrict__ o2b,
                                            const float* __restrict__ g2, const float* __restrict__ b2,
                                            float* __restrict__ ws){
  const int ch = blockIdx.x;
  const int t = threadIdx.x;
  __shared__ float wl[128];
  __shared__ float red[5][4];
  if(t < 128) wl[t] = o2w[ch*128 + t];
  __syncthreads();
  float acc[4];
#pragma unroll
  for(int n = 0; n < 4; ++n) acc[n] = o2b[ch];
  for(int c = 0; c < 128; ++c){
    float wv = wl[c];
#pragma unroll
    for(int n = 0; n < 4; ++n) acc[n] += wv * ws[WS_H3 + n*32768 + c*256 + t];
  }
  float s2 = 0.0f;
#pragma unroll
  for(int n = 0; n < 4; ++n) s2 += acc[n]*acc[n];
  float r0 = wrSum(acc[0]), r1 = wrSum(acc[1]), r2 = wrSum(acc[2]), r3 = wrSum(acc[3]), r4 = wrSum(s2);
  const int w = t >> 6;
  if((t & 63) == 0){ red[0][w]=r0; red[1][w]=r1; red[2][w]=r2; red[3][w]=r3; red[4][w]=r4; }
  __syncthreads();
  if(t == 0){
    float A0 = red[0][0]+red[0][1]+red[0][2]+red[0][3];
    float A1 = red[1][0]+red[1][1]+red[1][2]+red[1][3];
    float A2 = red[2][0]+red[2][1]+red[2][2]+red[2][3];
    float A3 = red[3][0]+red[3][1]+red[3][2]+red[3][3];
    float S2 = red[4][0]+red[4][1]+red[4][2]+red[4][3];
    float S = A0+A1+A2+A3;
    float mean = S * (1.0f/1024.0f);
    float var = S2 * (1.0f/1024.0f) - mean*mean;
    float sc = g2[ch]*rsqrtf(var + 1e-5f);
    float sh = b2[ch] - mean*sc;
    // mean over positions of (x*sc+sh) = rowmean*sc + sh
    ws[WS_S + 0*128 + ch] = A0*(1.0f/256.0f)*sc + sh;
    ws[WS_S + 1*128 + ch] = A1*(1.0f/256.0f)*sc + sh;
    ws[WS_S + 2*128 + ch] = A2*(1.0f/256.0f)*sc + sh;
    ws[WS_S + 3*128 + ch] = A3*(1.0f/256.0f)*sc + sh;
  }
}

// ---------------- K7: threshold / redistribute / normalize ----------------
__global__ __launch_bounds__(512) void k_final(const float* __restrict__ ws, float* __restrict__ out){
  const int t = threadIdx.x;
  const int w = t >> 6;
  __shared__ float ra[8], rb[8], rc[8], rd[8];
  __shared__ float mxSh, rSh, dnSh, dxSh;
  float v = ws[WS_S + t];
  float m1 = wrMax(v);
  if((t & 63) == 0) ra[w] = m1;
  __syncthreads();
  if(t == 0){
    float xv = ra[0];
#pragma unroll
    for(int k = 1; k < 8; ++k) xv = fmaxf(xv, ra[k]);
    mxSh = xv;
  }
  __syncthreads();
  const float thr = 0.5f * mxSh;   // THETA = 0.5
  float e = wrSum(fmaxf(v - thr, 0.0f));
  if((t & 63) == 0) rb[w] = e;
  __syncthreads();
  if(t == 0){
    float xv = 0.0f;
#pragma unroll
    for(int k = 0; k < 8; ++k) xv += rb[k];
    rSh = xv * (1.0f/16.0f);       // r = extra / L
  }
  __syncthreads();
  const float de = (v > thr) ? (thr + rSh) : (v + rSh);
  float dn = wrMin(de);
  float dx = wrMax(de);
  if((t & 63) == 0){ rc[w] = dn; rd[w] = dx; }
  __syncthreads();
  if(t == 0){
    float a = rc[0], b = rd[0];
#pragma unroll
    for(int k = 1; k < 8; ++k){ a = fminf(a, rc[k]); b = fmaxf(b, rd[k]); }
    dnSh = a; dxSh = b;
  }
  __syncthreads();
  out[t] = (de - dnSh) / (dxSh - dnSh + 1e-6f);
}

extern "C" void kernel_launch(void* const* d_in, const int* in_sizes, int n_in,
                              void* d_out, int out_size, void* d_ws, size_t ws_size,
                              hipStream_t stream){
  (void)in_sizes; (void)n_in; (void)out_size; (void)ws_size;
  const float* x   = (const float*)d_in[0];
  const float* f1w = (const float*)d_in[1];
  const float* f1b = (const float*)d_in[2];
  const float* f2w = (const float*)d_in[3];
  const float* f2b = (const float*)d_in[4];
  const float* o1w = (const float*)d_in[5];
  const float* o1b = (const float*)d_in[6];
  const float* g1  = (const float*)d_in[7];
  const float* b1  = (const float*)d_in[8];
  const float* o2w = (const float*)d_in[9];
  const float* o2b = (const float*)d_in[10];
  const float* g2  = (const float*)d_in[11];
  const float* b2  = (const float*)d_in[12];
  float* ws  = (float*)d_ws;
  float* out = (float*)d_out;

  k_init <<<1,    64,  0, stream>>>(ws);
  k_mu   <<<256,  256, 0, stream>>>(x, ws);
  k_cos  <<<1024, 256, 0, stream>>>(x, ws);
  k_gram <<<256,  256, 0, stream>>>(ws);
  k_mlp  <<<1024, 128, 0, stream>>>(f1w, f1b, f2w, f2b, ws);
  k_o1   <<<128,  256, 0, stream>>>(o1w, o1b, g1, b1, ws);
  k_o2   <<<128,  256, 0, stream>>>(o2w, o2b, g2, b2, ws);
  k_final<<<1,    512, 0, stream>>>(ws, out);
}